// Round 1
// baseline (70.102 us; speedup 1.0000x reference)
//
#include <hip/hip_runtime.h>
#include <cstdint>

#define BB 4
#define HH 2048
#define WW 2048
#define MAXT 21
#define BIGSQ 441   // MAXT^2

// ---------------- Pass A: horizontal capped nearest-obstacle distance ----------------
// One block = 256 pixels of one row. Ballot-pack obstacle bits, window via masks.
__global__ __launch_bounds__(256) void hpass(const int* __restrict__ in,
                                             uint8_t* __restrict__ dh) {
    __shared__ unsigned long long masks[6]; // cover pixels [x0-64, x0+320)
    const int tid  = threadIdx.x;
    const int wid  = tid >> 6;
    const int lane = tid & 63;
    const int row  = blockIdx.y;            // 0 .. BB*HH-1 (rows never cross batches)
    const int x0   = blockIdx.x << 8;
    const long long ro = (long long)row * WW;

    const int x = x0 + tid;
    const int v = in[ro + x];
    unsigned long long m = __ballot(v != 0);
    if (lane == 0) masks[wid + 1] = m;

    if (wid == 0) {                           // left halo chunk
        int hx = x0 - 64 + lane;
        int hv = (hx >= 0) ? in[ro + hx] : 0;
        unsigned long long hm = __ballot(hv != 0);
        if (lane == 0) masks[0] = hm;
    } else if (wid == 3) {                    // right halo chunk
        int hx = x0 + 256 + lane;
        int hv = (hx < WW) ? in[ro + hx] : 0;
        unsigned long long hm = __ballot(hv != 0);
        if (lane == 0) masks[5] = hm;
    }
    __syncthreads();

    const int c = wid + 1;
    const unsigned long long mc = masks[c];

    // distance to nearest set bit at pos >= lane (d = 0..): bit (lane+d)
    unsigned long long right = mc >> lane;
    if (lane) right |= masks[c + 1] << (64 - lane);
    // distance to nearest set bit at pos <= lane: bit (lane-d) placed at 63-d
    unsigned long long left = mc << (63 - lane);
    if (lane != 63) left |= masks[c - 1] >> (lane + 1);

    int dr = right ? __builtin_ctzll(right) : 64;
    int dl = left  ? __builtin_clzll(left)  : 64;
    int d  = min(min(dr, dl), MAXT);
    dh[ro + x] = (uint8_t)d;
}

// ---------------- Pass B: vertical relax + sqrt ----------------
// One block = 64x64 output tile of one batch image. Stage dh^2 (106 rows halo) in LDS.
__global__ __launch_bounds__(256) void vpass(const uint8_t* __restrict__ dh,
                                             float* __restrict__ out) {
    __shared__ uint16_t s[106][64];
    const int tid = threadIdx.x;
    const int x0  = blockIdx.x << 6;
    const int y0  = blockIdx.y << 6;
    const int b   = blockIdx.z;
    const long long base = (long long)b * HH * WW;

    // load 106 rows x 64 cols (uchar4-vectorized), square into LDS
    for (int i = tid; i < 106 * 16; i += 256) {
        int r  = i >> 4;
        int c4 = (i & 15) << 2;
        int gy = y0 - 21 + r;
        ushort4 val;
        if (gy >= 0 && gy < HH) {
            const uint8_t* p = dh + base + (long long)gy * WW + x0 + c4;
            uchar4 u = *(const uchar4*)p;
            val.x = (uint16_t)(u.x * u.x);
            val.y = (uint16_t)(u.y * u.y);
            val.z = (uint16_t)(u.z * u.z);
            val.w = (uint16_t)(u.w * u.w);
        } else {
            val.x = val.y = val.z = val.w = BIGSQ;  // out-of-image rows never win
        }
        *(ushort4*)&s[r][c4] = val;
    }
    __syncthreads();

    const int c  = tid & 63;
    const int j0 = (tid >> 6) << 4;   // wave w owns rows j0..j0+15; all lanes same row
    for (int k = 0; k < 16; ++k) {
        const int j  = j0 + k;
        const int yl = 21 + j;
        int val = s[yl][c];
        for (int d = 1; d <= MAXT; ++d) {
            const int dd = d * d;
            if (__all(dd >= val)) break;  // future candidates >= d^2 >= val for all lanes
            int t1 = s[yl - d][c] + dd;
            int t2 = s[yl + d][c] + dd;
            val = min(val, min(t1, t2));
        }
        out[base + (long long)(y0 + j) * WW + x0 + c] = sqrtf((float)val);
    }
}

extern "C" void kernel_launch(void* const* d_in, const int* in_sizes, int n_in,
                              void* d_out, int out_size, void* d_ws, size_t ws_size,
                              hipStream_t stream) {
    const int* unt = (const int*)d_in[0];        // bool input as int32 per harness doc
    uint8_t* dh    = (uint8_t*)d_ws;             // BB*HH*WW bytes = 16.7 MB scratch
    float* out     = (float*)d_out;

    hpass<<<dim3(WW / 256, BB * HH), 256, 0, stream>>>(unt, dh);
    vpass<<<dim3(WW / 64, HH / 64, BB), 256, 0, stream>>>(dh, out);
}

// Round 2
// 45.898 us; speedup vs baseline: 1.5273x; 1.5273x over previous
//
#include <hip/hip_runtime.h>
#include <cstdint>

#define BB 4
#define HH 2048
#define WW 2048
#define MAXT 21
#define BIGSQ 441   // MAXT^2

// ---------------- Pass A: horizontal capped nearest-obstacle distance ----------------
// One wave owns 512 contiguous pixels of one row; no LDS, no barriers.
// 8 core ballots + 2 halo ballots give all mask words in registers.
__global__ __launch_bounds__(256) void hpass(const int* __restrict__ in,
                                             uint8_t* __restrict__ dh) {
    const int tid  = threadIdx.x;
    const int lane = tid & 63;
    const int w    = tid >> 6;
    const int row  = blockIdx.x;              // 0 .. BB*HH-1 (rows never cross batches)
    const long long ro = (long long)row * WW;
    const int x0   = w << 9;                   // wave segment start (512 px), WW=2048=4*512

    int v[8];
    #pragma unroll
    for (int j = 0; j < 8; ++j)
        v[j] = in[ro + x0 + (j << 6) + lane];

    unsigned long long b[10];                  // b[0]=left halo, b[1..8]=core, b[9]=right halo
    b[0] = 0; b[9] = 0;
    if (x0 > 0)                                // wave-uniform branches
        b[0] = __ballot(in[ro + x0 - 64 + lane] != 0);
    if (x0 + 512 < WW)
        b[9] = __ballot(in[ro + x0 + 512 + lane] != 0);
    #pragma unroll
    for (int j = 0; j < 8; ++j)
        b[j + 1] = __ballot(v[j] != 0);

    #pragma unroll
    for (int j = 0; j < 8; ++j) {
        const unsigned long long mc = b[j + 1];
        // nearest set bit at pos >= lane
        unsigned long long right = mc >> lane;
        if (lane) right |= b[j + 2] << (64 - lane);
        // nearest set bit at pos <= lane, aligned so it's a clz
        unsigned long long left = mc << (63 - lane);
        if (lane != 63) left |= b[j] >> (lane + 1);

        int dr = right ? __builtin_ctzll(right) : 64;
        int dl = left  ? __builtin_clzll(left)  : 64;
        int d  = min(min(dr, dl), MAXT);
        dh[ro + x0 + (j << 6) + lane] = (uint8_t)d;
    }
}

// ---------------- Pass B: vertical relax + sqrt ----------------
// One block = 64x64 output tile of one batch image. Stage dh^2 (106 rows halo) in LDS.
__global__ __launch_bounds__(256) void vpass(const uint8_t* __restrict__ dh,
                                             float* __restrict__ out) {
    __shared__ uint16_t s[106][64];
    const int tid = threadIdx.x;
    const int x0  = blockIdx.x << 6;
    const int y0  = blockIdx.y << 6;
    const int b   = blockIdx.z;
    const long long base = (long long)b * HH * WW;

    // load 106 rows x 64 cols (uchar4-vectorized), square into LDS
    for (int i = tid; i < 106 * 16; i += 256) {
        int r  = i >> 4;
        int c4 = (i & 15) << 2;
        int gy = y0 - 21 + r;
        ushort4 val;
        if (gy >= 0 && gy < HH) {
            const uint8_t* p = dh + base + (long long)gy * WW + x0 + c4;
            uchar4 u = *(const uchar4*)p;
            val.x = (uint16_t)(u.x * u.x);
            val.y = (uint16_t)(u.y * u.y);
            val.z = (uint16_t)(u.z * u.z);
            val.w = (uint16_t)(u.w * u.w);
        } else {
            val.x = val.y = val.z = val.w = BIGSQ;  // out-of-image rows never win
        }
        *(ushort4*)&s[r][c4] = val;
    }
    __syncthreads();

    const int c  = tid & 63;
    const int j0 = (tid >> 6) << 4;   // wave w owns rows j0..j0+15; all lanes same row
    for (int k = 0; k < 16; ++k) {
        const int j  = j0 + k;
        const int yl = 21 + j;
        int val = s[yl][c];
        for (int d = 1; d <= MAXT; ++d) {
            const int dd = d * d;
            if (__all(dd >= val)) break;  // future candidates >= d^2 >= val for all lanes
            int t1 = s[yl - d][c] + dd;
            int t2 = s[yl + d][c] + dd;
            val = min(val, min(t1, t2));
        }
        out[base + (long long)(y0 + j) * WW + x0 + c] = sqrtf((float)val);
    }
}

extern "C" void kernel_launch(void* const* d_in, const int* in_sizes, int n_in,
                              void* d_out, int out_size, void* d_ws, size_t ws_size,
                              hipStream_t stream) {
    const int* unt = (const int*)d_in[0];        // bool input as int32 per harness doc
    uint8_t* dh    = (uint8_t*)d_ws;             // BB*HH*WW bytes = 16.7 MB scratch
    float* out     = (float*)d_out;

    hpass<<<dim3(BB * HH), 256, 0, stream>>>(unt, dh);
    vpass<<<dim3(WW / 64, HH / 64, BB), 256, 0, stream>>>(dh, out);
}

// Round 3
// 41.457 us; speedup vs baseline: 1.6909x; 1.1071x over previous
//
#include <hip/hip_runtime.h>
#include <cstdint>

#define BB 4
#define HH 2048
#define WW 2048
#define MAXT 21
#define BIGSQ 441   // MAXT^2

static __device__ __forceinline__ uint32_t umin32(uint32_t a, uint32_t b) { return a < b ? a : b; }

// ---------------- Pass A: horizontal capped nearest-obstacle distance ----------------
// One wave owns 512 contiguous pixels of one row; no LDS, no barriers.
__global__ __launch_bounds__(256) void hpass(const int* __restrict__ in,
                                             uint8_t* __restrict__ dh) {
    const int tid  = threadIdx.x;
    const int lane = tid & 63;
    const int w    = tid >> 6;
    const int row  = blockIdx.x;              // 0 .. BB*HH-1 (rows never cross batches)
    const long long ro = (long long)row * WW;
    const int x0   = w << 9;                   // wave segment start (512 px)

    int v[8];
    #pragma unroll
    for (int j = 0; j < 8; ++j)
        v[j] = in[ro + x0 + (j << 6) + lane];

    unsigned long long b[10];                  // b[0]=left halo, b[1..8]=core, b[9]=right halo
    b[0] = 0; b[9] = 0;
    if (x0 > 0)
        b[0] = __ballot(in[ro + x0 - 64 + lane] != 0);
    if (x0 + 512 < WW)
        b[9] = __ballot(in[ro + x0 + 512 + lane] != 0);
    #pragma unroll
    for (int j = 0; j < 8; ++j)
        b[j + 1] = __ballot(v[j] != 0);

    #pragma unroll
    for (int j = 0; j < 8; ++j) {
        const unsigned long long mc = b[j + 1];
        unsigned long long right = mc >> lane;
        if (lane) right |= b[j + 2] << (64 - lane);
        unsigned long long left = mc << (63 - lane);
        if (lane != 63) left |= b[j] >> (lane + 1);

        int dr = right ? __builtin_ctzll(right) : 64;
        int dl = left  ? __builtin_clzll(left)  : 64;
        int d  = min(min(dr, dl), MAXT);
        dh[ro + x0 + (j << 6) + lane] = (uint8_t)d;
    }
}

// ---------------- Pass B: vertical relax + sqrt ----------------
// 128x64 output tile. LDS holds dh^2 (uint16) for 106 rows x 128 cols.
// Each lane owns 4 adjacent columns: candidates via ds_read_b64 (4 px/read),
// packed-u16 adds (no carry: values <= 882), scalar mins after unpack.
__global__ __launch_bounds__(256) void vpass(const uint8_t* __restrict__ dh,
                                             float* __restrict__ out) {
    __shared__ uint16_t s[106][128];   // 27136 B
    const int tid = threadIdx.x;
    const int x0  = blockIdx.x << 7;
    const int y0  = blockIdx.y << 6;
    const int b   = blockIdx.z;
    const long long base = (long long)b * HH * WW;

    // stage: 8 dh bytes per lane-iter -> 8 squared uint16 -> one b128 LDS write
    for (int i = tid; i < 106 * 16; i += 256) {
        int r  = i >> 4;
        int c8 = (i & 15) << 3;
        int gy = y0 - 21 + r;
        uint4 pk;
        if (gy >= 0 && gy < HH) {
            const uint8_t* p = dh + base + (long long)gy * WW + x0 + c8;
            uint2 u = *(const uint2*)p;
            uint32_t e0 = u.x & 0xff, e1 = (u.x >> 8) & 0xff, e2 = (u.x >> 16) & 0xff, e3 = u.x >> 24;
            uint32_t e4 = u.y & 0xff, e5 = (u.y >> 8) & 0xff, e6 = (u.y >> 16) & 0xff, e7 = u.y >> 24;
            pk.x = (e0 * e0) | ((e1 * e1) << 16);
            pk.y = (e2 * e2) | ((e3 * e3) << 16);
            pk.z = (e4 * e4) | ((e5 * e5) << 16);
            pk.w = (e6 * e6) | ((e7 * e7) << 16);
        } else {
            pk.x = pk.y = pk.z = pk.w = BIGSQ | (BIGSQ << 16);  // out-of-image: never wins
        }
        *(uint4*)&s[r][c8] = pk;
    }
    __syncthreads();

    const int lane = tid & 63;
    const int w    = tid >> 6;
    const int cg   = (lane & 31) << 2;   // column 4-group base (covers 128 cols)
    const int ro   = lane >> 5;          // row offset 0/1
    // wave w owns output rows [16w, 16w+16); per k-iter it covers 2 rows x 128 cols
    for (int k = 0; k < 8; ++k) {
        const int j  = (w << 4) + (k << 1) + ro;
        const int yl = 21 + j;

        uint2 q = *(const uint2*)&s[yl][cg];
        uint32_t v0 = q.x & 0xffff, v1 = q.x >> 16;
        uint32_t v2 = q.y & 0xffff, v3 = q.y >> 16;

        for (int d = 1; d <= MAXT; ++d) {
            const uint32_t dd = (uint32_t)(d * d);
            uint32_t h = umin32(0, 0); // placeholder avoided below
            h = v0 > v1 ? v0 : v1;
            uint32_t h2 = v2 > v3 ? v2 : v3;
            h = h > h2 ? h : h2;
            if (__all(dd >= h)) break;   // further candidates >= d^2 >= current val
            uint2 a  = *(const uint2*)&s[yl - d][cg];
            uint2 bq = *(const uint2*)&s[yl + d][cg];
            const uint32_t dd2 = dd * 0x10001u;   // packed add, no carry (<= 882 per half)
            uint32_t A0 = a.x + dd2, A1 = a.y + dd2;
            uint32_t B0 = bq.x + dd2, B1 = bq.y + dd2;
            v0 = umin32(v0, umin32(A0 & 0xffff, B0 & 0xffff));
            v1 = umin32(v1, umin32(A0 >> 16,    B0 >> 16));
            v2 = umin32(v2, umin32(A1 & 0xffff, B1 & 0xffff));
            v3 = umin32(v3, umin32(A1 >> 16,    B1 >> 16));
        }

        float4 o;
        o.x = sqrtf((float)v0);
        o.y = sqrtf((float)v1);
        o.z = sqrtf((float)v2);
        o.w = sqrtf((float)v3);
        *(float4*)&out[base + (long long)(y0 + j) * WW + x0 + cg] = o;
    }
}

extern "C" void kernel_launch(void* const* d_in, const int* in_sizes, int n_in,
                              void* d_out, int out_size, void* d_ws, size_t ws_size,
                              hipStream_t stream) {
    const int* unt = (const int*)d_in[0];
    uint8_t* dh    = (uint8_t*)d_ws;             // BB*HH*WW bytes = 16.7 MB scratch
    float* out     = (float*)d_out;

    hpass<<<dim3(BB * HH), 256, 0, stream>>>(unt, dh);
    vpass<<<dim3(WW / 128, HH / 64, BB), 256, 0, stream>>>(dh, out);
}

// Round 4
// 40.967 us; speedup vs baseline: 1.7112x; 1.0120x over previous
//
#include <hip/hip_runtime.h>
#include <cstdint>

#define BB 4
#define HH 2048
#define WW 2048
#define MAXT 21
#define BIGSQ 441   // MAXT^2

static __device__ __forceinline__ uint32_t umin32(uint32_t a, uint32_t b) { return a < b ? a : b; }

// ---------------- Pass A: horizontal capped nearest-obstacle distance ----------------
// One wave = one full row (2048 px). uint2 loads (8 B/lane, px 2l/2l+1), all 16
// chunk-loads issued upfront. Even/odd ballot masks per 128-px chunk; nearest
// set bit via funnel shift + sentinel ctz (cap 21). Left side = bit-reversed
// masks with phase swap. No halos, no divergent branches, no LDS.
__global__ __launch_bounds__(256, 4) void hpass(const int* __restrict__ in,
                                                uint8_t* __restrict__ dh) {
    const int tid  = threadIdx.x;
    const int lane = tid & 63;
    const int w    = tid >> 6;
    const int row  = (blockIdx.x << 2) + w;      // 4 rows per block, rows never cross batches
    const long long ro = (long long)row * WW;
    const int* rp = in + ro;
    const int li = 63 - lane;

    uint2 u[16];
    #pragma unroll
    for (int c = 0; c < 16; ++c)
        u[c] = *(const uint2*)(rp + (c << 7) + (lane << 1));

    unsigned long long b0p = 0, b1p = 0;                       // prev-chunk masks
    unsigned long long b0c = __ballot(u[0].x != 0);
    unsigned long long b1c = __ballot(u[0].y != 0);

    #pragma unroll
    for (int c = 0; c < 16; ++c) {
        unsigned long long b0n = 0, b1n = 0;
        if (c < 15) {
            b0n = __ballot(u[c + 1].x != 0);
            b1n = __ballot(u[c + 1].y != 0);
        }
        // reversed-space masks with phase swap: RB_m = brev(B_{1-m})
        unsigned long long rb0c = __brevll(b1c), rb1c = __brevll(b0c);
        unsigned long long rb0p = __brevll(b1p), rb1p = __brevll(b0p);

        // funnels: S_m bit t = obstacle at (px pair base + 2t + m-offset) rightwards
        unsigned long long S0  = (b0c >> lane) | ((b0n << 1) << li);
        unsigned long long S1  = (b1c >> lane) | ((b1n << 1) << li);
        unsigned long long SL0 = (rb0c >> li)  | ((rb0p << 1) << lane);
        unsigned long long SL1 = (rb1c >> li)  | ((rb1p << 1) << lane);

        const uint32_t SEN = 1u << 11;       // sentinel: t=11 -> d>=22 -> clamps to 21
        uint32_t s0 = (uint32_t)S0, s1 = (uint32_t)S1;
        uint32_t l0 = (uint32_t)SL0, l1 = (uint32_t)SL1;
        int t_s0  = __builtin_ctz(s0 | SEN);
        int t_s1  = __builtin_ctz(s1 | SEN);
        int t_s0s = __builtin_ctz((s0 >> 1) | SEN);
        int t_l0  = __builtin_ctz(l0 | SEN);
        int t_l1  = __builtin_ctz(l1 | SEN);
        int t_l0s = __builtin_ctz((l0 >> 1) | SEN);

        // px0 (even): right = min(2*t_s0, 2*t_s1+1); left (k'=1 on reversed) = min(2*t_l1, 2*t_l0s+1)
        int d0 = min(min(2 * t_s0, 2 * t_s1 + 1), min(2 * t_l1, 2 * t_l0s + 1));
        // px1 (odd):  right = min(2*t_s1, 2*t_s0s+1); left (k'=0 on reversed) = min(2*t_l0, 2*t_l1+1)
        int d1 = min(min(2 * t_s1, 2 * t_s0s + 1), min(2 * t_l0, 2 * t_l1 + 1));
        d0 = min(d0, MAXT);
        d1 = min(d1, MAXT);

        *(uint16_t*)(dh + ro + (c << 7) + (lane << 1)) = (uint16_t)(d0 | (d1 << 8));

        b0p = b0c; b1p = b1c; b0c = b0n; b1c = b1n;
    }
}

// ---------------- Pass B: vertical relax + sqrt ----------------
// 128x64 output tile. LDS holds dh^2 (uint16) for 106 rows x 128 cols.
// Each lane owns 4 adjacent columns: candidates via ds_read_b64 (4 px/read),
// packed-u16 adds (no carry: values <= 882), scalar mins after unpack.
__global__ __launch_bounds__(256) void vpass(const uint8_t* __restrict__ dh,
                                             float* __restrict__ out) {
    __shared__ uint16_t s[106][128];   // 27136 B
    const int tid = threadIdx.x;
    const int x0  = blockIdx.x << 7;
    const int y0  = blockIdx.y << 6;
    const int b   = blockIdx.z;
    const long long base = (long long)b * HH * WW;

    // stage: 8 dh bytes per lane-iter -> 8 squared uint16 -> one b128 LDS write
    for (int i = tid; i < 106 * 16; i += 256) {
        int r  = i >> 4;
        int c8 = (i & 15) << 3;
        int gy = y0 - 21 + r;
        uint4 pk;
        if (gy >= 0 && gy < HH) {
            const uint8_t* p = dh + base + (long long)gy * WW + x0 + c8;
            uint2 uu = *(const uint2*)p;
            uint32_t e0 = uu.x & 0xff, e1 = (uu.x >> 8) & 0xff, e2 = (uu.x >> 16) & 0xff, e3 = uu.x >> 24;
            uint32_t e4 = uu.y & 0xff, e5 = (uu.y >> 8) & 0xff, e6 = (uu.y >> 16) & 0xff, e7 = uu.y >> 24;
            pk.x = (e0 * e0) | ((e1 * e1) << 16);
            pk.y = (e2 * e2) | ((e3 * e3) << 16);
            pk.z = (e4 * e4) | ((e5 * e5) << 16);
            pk.w = (e6 * e6) | ((e7 * e7) << 16);
        } else {
            pk.x = pk.y = pk.z = pk.w = BIGSQ | (BIGSQ << 16);  // out-of-image: never wins
        }
        *(uint4*)&s[r][c8] = pk;
    }
    __syncthreads();

    const int lane = tid & 63;
    const int w    = tid >> 6;
    const int cg   = (lane & 31) << 2;   // column 4-group base (covers 128 cols)
    const int ro   = lane >> 5;          // row offset 0/1
    for (int k = 0; k < 8; ++k) {
        const int j  = (w << 4) + (k << 1) + ro;
        const int yl = 21 + j;

        uint2 q = *(const uint2*)&s[yl][cg];
        uint32_t v0 = q.x & 0xffff, v1 = q.x >> 16;
        uint32_t v2 = q.y & 0xffff, v3 = q.y >> 16;

        for (int d = 1; d <= MAXT; ++d) {
            const uint32_t dd = (uint32_t)(d * d);
            uint32_t h  = v0 > v1 ? v0 : v1;
            uint32_t h2 = v2 > v3 ? v2 : v3;
            h = h > h2 ? h : h2;
            if (__all(dd >= h)) break;   // further candidates >= d^2 >= current val
            uint2 a  = *(const uint2*)&s[yl - d][cg];
            uint2 bq = *(const uint2*)&s[yl + d][cg];
            const uint32_t dd2 = dd * 0x10001u;   // packed add, no carry (<= 882 per half)
            uint32_t A0 = a.x + dd2, A1 = a.y + dd2;
            uint32_t B0 = bq.x + dd2, B1 = bq.y + dd2;
            v0 = umin32(v0, umin32(A0 & 0xffff, B0 & 0xffff));
            v1 = umin32(v1, umin32(A0 >> 16,    B0 >> 16));
            v2 = umin32(v2, umin32(A1 & 0xffff, B1 & 0xffff));
            v3 = umin32(v3, umin32(A1 >> 16,    B1 >> 16));
        }

        float4 o;
        o.x = sqrtf((float)v0);
        o.y = sqrtf((float)v1);
        o.z = sqrtf((float)v2);
        o.w = sqrtf((float)v3);
        *(float4*)&out[base + (long long)(y0 + j) * WW + x0 + cg] = o;
    }
}

extern "C" void kernel_launch(void* const* d_in, const int* in_sizes, int n_in,
                              void* d_out, int out_size, void* d_ws, size_t ws_size,
                              hipStream_t stream) {
    const int* unt = (const int*)d_in[0];
    uint8_t* dh    = (uint8_t*)d_ws;             // BB*HH*WW bytes = 16.7 MB scratch
    float* out     = (float*)d_out;

    hpass<<<dim3(BB * HH / 4), 256, 0, stream>>>(unt, dh);
    vpass<<<dim3(WW / 128, HH / 64, BB), 256, 0, stream>>>(dh, out);
}